// Round 2
// 910.342 us; speedup vs baseline: 1.2964x; 1.2964x over previous
//
#include <hip/hip_runtime.h>
#include <stdint.h>

#define THREADS 256
#define N_MAX 131072
#define B_MAX 2100000

// Static device scratch (n <= 131072 nodes, totalBlocks = n+2E <= 2.1M).
// g_cnt / g_cnt2 are self-restoring: hist counts UP, scatter_fill claims slots by
// atomicSub counting DOWN to exactly zero -> no zero_kernel needed between calls.
__device__ int g_cnt[N_MAX];        // blocks per node (row/col histogram over E)
__device__ int g_cnt2[N_MAX];       // diag contributions per node (histogram of ei[0] over 2E)
__device__ int g_blk_off[N_MAX + 1];
__device__ int g_off2[N_MAX + 1];
__device__ float g_maps_diag[(size_t)N_MAX * 16];
__device__ unsigned long long g_keys[B_MAX];
__device__ int g_perm[B_MAX];       // counting-sort of g in [0,2E) by ei[0][g]
__device__ int g_wide;

// edge_index staged int32 or int64 (values < 2^31, LE): wide==1 -> low word at 2*idx.
__device__ __forceinline__ int get_ei(const int* __restrict__ ei, int wide, long long idx) {
  return ei[idx << wide];
}

__device__ __forceinline__ unsigned long long shfl_xor_u64(unsigned long long x, int mask) {
  int lo = (int)(x & 0xFFFFFFFFULL);
  int hi = (int)(x >> 32);
  lo = __shfl_xor(lo, mask, 64);
  hi = __shfl_xor(hi, mask, 64);
  return ((unsigned long long)(unsigned int)hi << 32) | (unsigned int)lo;
}

// 1) histograms + in-block wide detection (removes the 1-thread detect_wide launch).
__global__ void hist_kernel(const int* __restrict__ ei, int E, int twoE) {
  __shared__ int s_w;
  if (threadIdx.x == 0) {
    int w = 1;
    int lim = (twoE >= 8) ? 8 : twoE;
    for (int i = 0; i < lim; i++)
      if (ei[2 * i + 1] != 0) w = 0;
    s_w = w;
    if (blockIdx.x == 0) g_wide = w;   // for downstream dispatches
  }
  __syncthreads();
  int w = s_w;
  int g = blockIdx.x * blockDim.x + threadIdx.x;
  if (g >= twoE) return;
  int a0 = get_ei(ei, w, g);
  atomicAdd(&g_cnt2[a0], 1);
  if (g < E) {
    atomicAdd(&g_cnt[a0], 1);                                  // row
    atomicAdd(&g_cnt[get_ei(ei, w, (long long)twoE + g)], 1);  // col
  }
}

// 2) both exclusive scans in ONE launch: block 0 -> blk_off (cnt+1), block 1 -> off2 (cnt2)
__global__ void scan_kernel(int n) {
  __shared__ int partial[1024];
  int which = blockIdx.x;
  int tid = threadIdx.x;
  int chunk = (n + 1023) / 1024;
  int start = tid * chunk;
  int end = min(start + chunk, n);
  int add1 = (which == 0) ? 1 : 0;
  const int* src = (which == 0) ? g_cnt : g_cnt2;
  int* dst = (which == 0) ? g_blk_off : g_off2;
  int s = 0;
  for (int u = start; u < end; u++) s += src[u] + add1;
  partial[tid] = s;
  __syncthreads();
  for (int off = 1; off < 1024; off <<= 1) {
    int v = (tid >= off) ? partial[tid - off] : 0;
    __syncthreads();
    partial[tid] += v;
    __syncthreads();
  }
  int run = (tid == 0) ? 0 : partial[tid - 1];
  for (int u = start; u < end; u++) { dst[u] = run; run += src[u] + add1; }
  if (tid == 1023) dst[n] = partial[1023];
}

// 3) merged counting-sort scatter (perm) + edge key fill. Slots claimed by atomicSub
//    counting the histograms back down to zero (self-restoring scratch).
//    key = (u << 44) | (v << 22) | (cls << 20) | e   (u,v < 2^17, e < 2^20)
__global__ void scatter_fill_kernel(const int* __restrict__ ei, int E, int twoE) {
  int g = blockIdx.x * blockDim.x + threadIdx.x;
  if (g >= twoE) return;
  int w = g_wide;
  int u = get_ei(ei, w, g);
  int p = g_off2[u] + atomicSub(&g_cnt2[u], 1) - 1;
  g_perm[p] = g;
  if (g < E) {
    int v = get_ei(ei, w, (long long)twoE + g);
    int c1 = atomicSub(&g_cnt[u], 1);            // old value in [1, cnt[u]]
    int p1 = g_blk_off[u] + c1;                  // diag slot is +0
    g_keys[p1] = ((unsigned long long)u << 44) | ((unsigned long long)v << 22) |
                 (1ULL << 20) | (unsigned long long)g;
    int c2 = atomicSub(&g_cnt[v], 1);
    int p2 = g_blk_off[v] + c2;
    g_keys[p2] = ((unsigned long long)v << 44) | ((unsigned long long)u << 22) |
                 (2ULL << 20) | (unsigned long long)g;
  }
}

// 4) gather-reduce diag, 4 threads per node (4x waves of the 1-thread/node version for
//    latency hiding), shfl-combine, lane h==0 also places the diag key (place_diag merged).
__global__ void diag_place_kernel(const float* __restrict__ maps, int n) {
  int t = blockIdx.x * blockDim.x + threadIdx.x;
  int u = t >> 2;
  int h = t & 3;
  if (u >= n) return;
  int s = g_off2[u];
  int epos = g_off2[u + 1];
  float acc[10];
#pragma unroll
  for (int i = 0; i < 10; i++) acc[i] = 0.0f;
  for (int i = s + h; i < epos; i += 4) {
    int g = g_perm[i];
    const float4* Mv = reinterpret_cast<const float4*>(maps + (size_t)g * 16);
    float4 t0 = Mv[0], t1 = Mv[1], t2 = Mv[2], t3 = Mv[3];
    float m[16] = {t0.x, t0.y, t0.z, t0.w, t1.x, t1.y, t1.z, t1.w,
                   t2.x, t2.y, t2.z, t2.w, t3.x, t3.y, t3.z, t3.w};
    int p = 0;
#pragma unroll
    for (int a = 0; a < 4; a++)
#pragma unroll
      for (int b = a; b < 4; b++) {
        acc[p] += m[0 + a] * m[0 + b] + m[4 + a] * m[4 + b] + m[8 + a] * m[8 + b] + m[12 + a] * m[12 + b];
        p++;
      }
  }
#pragma unroll
  for (int i = 0; i < 10; i++) {
    acc[i] += __shfl_xor(acc[i], 1, 64);
    acc[i] += __shfl_xor(acc[i], 2, 64);
  }
  if (h == 0) {
    float d[16];
    int p = 0;
#pragma unroll
    for (int a = 0; a < 4; a++)
#pragma unroll
      for (int b = a; b < 4; b++) {
        d[a * 4 + b] = acc[p];
        d[b * 4 + a] = acc[p];
        p++;
      }
    float4* D = reinterpret_cast<float4*>(g_maps_diag + (size_t)u * 16);
#pragma unroll
    for (int i = 0; i < 4; i++) D[i] = make_float4(d[4 * i], d[4 * i + 1], d[4 * i + 2], d[4 * i + 3]);
    int pp = g_blk_off[u];
    g_keys[pp] = ((unsigned long long)u << 44) | ((unsigned long long)u << 22);
  }
}

// 5) per-node sort: ONE WAVE per node, register bitonic via shfl_xor.
//    c<=64: 1 reg/lane, 21 compare-exchange steps. c<=128: 2 regs/lane, 28 steps.
//    No LDS, no divergent dependent-latency chains, coalesced key IO.
__global__ __launch_bounds__(256) void sort_kernel(int n) {
  int wv = (blockIdx.x * blockDim.x + threadIdx.x) >> 6;  // node = global wave id
  int lane = threadIdx.x & 63;
  if (wv >= n) return;
  int s = g_blk_off[wv];
  int c = g_blk_off[wv + 1] - s;
  if (c <= 1) return;
  if (c <= 64) {
    unsigned long long k = (lane < c) ? g_keys[s + lane] : ~0ULL;
    for (int kk = 2; kk <= 64; kk <<= 1) {
      for (int j = kk >> 1; j > 0; j >>= 1) {
        unsigned long long o = shfl_xor_u64(k, j);
        bool tm = ((lane & j) == 0) == ((lane & kk) == 0);
        unsigned long long lo = (k < o) ? k : o;
        unsigned long long hi = (k < o) ? o : k;
        k = tm ? lo : hi;
      }
    }
    if (lane < c) g_keys[s + lane] = k;
  } else if (c <= 128) {
    unsigned long long k0 = (lane < c) ? g_keys[s + lane] : ~0ULL;
    unsigned long long k1 = (lane + 64 < c) ? g_keys[s + lane + 64] : ~0ULL;
    for (int kk = 2; kk <= 128; kk <<= 1) {
      for (int j = kk >> 1; j > 0; j >>= 1) {
        if (j == 64) {  // only at kk==128: virtual lane < 64 takes min (all ascending)
          unsigned long long lo = (k0 < k1) ? k0 : k1;
          unsigned long long hi = (k0 < k1) ? k1 : k0;
          k0 = lo; k1 = hi;
        } else {
          unsigned long long o0 = shfl_xor_u64(k0, j);
          unsigned long long o1 = shfl_xor_u64(k1, j);
          bool jb = ((lane & j) == 0);
          bool tm0 = jb == ((lane & kk) == 0);
          bool tm1 = jb == (((lane + 64) & kk) == 0);
          unsigned long long lo0 = (k0 < o0) ? k0 : o0;
          unsigned long long hi0 = (k0 < o0) ? o0 : k0;
          unsigned long long lo1 = (k1 < o1) ? k1 : o1;
          unsigned long long hi1 = (k1 < o1) ? o1 : k1;
          k0 = tm0 ? lo0 : hi0;
          k1 = tm1 ? lo1 : hi1;
        }
      }
    }
    if (lane < c) g_keys[s + lane] = k0;
    if (lane + 64 < c) g_keys[s + lane + 64] = k1;
  } else {  // essentially-never fallback (Poisson(~33) degree)
    if (lane == 0) {
      for (int i = s + 1; i < s + c; i++) {
        unsigned long long kk2 = g_keys[i];
        int j = i - 1;
        while (j >= s && g_keys[j] > kk2) { g_keys[j + 1] = g_keys[j]; j--; }
        g_keys[j + 1] = kk2;
      }
    }
  }
}

// 6) emit (float32 out): one thread per block; b-major interleave for equal-v runs.
//    u decoded from key high bits (g_blk_node eliminated).
__global__ void emit_kernel(const float* __restrict__ maps, int E, long long T, int totalBlocks,
                            float* __restrict__ out) {
  int idx = blockIdx.x * blockDim.x + threadIdx.x;
  if (idx >= totalBlocks) return;
  unsigned long long key = g_keys[idx];
  int u = (int)(key >> 44);
  int base = g_blk_off[u];
  int cntu = g_blk_off[u + 1] - base;
  int k = idx - base;
  int v = (int)((key >> 22) & 0x3FFFFFULL);
  int cls = (int)((key >> 20) & 3ULL);
  int e = (int)(key & 0xFFFFFULL);
  unsigned long long vtag = key >> 22;  // (u,v) tag: u bits identical within node

  int k0 = k;
  while (k0 > 0 && (g_keys[base + k0 - 1] >> 22) == vtag) k0--;
  int k1 = k;
  while (k1 + 1 < cntu && (g_keys[base + k1 + 1] >> 22) == vtag) k1++;
  int m = k1 - k0 + 1;
  int j = k - k0;

  float val[16];
  if (cls == 0) {
    const float* D = g_maps_diag + (size_t)u * 16;
#pragma unroll
    for (int i = 0; i < 16; i++) val[i] = D[i];
  } else {
    const float* L = maps + (size_t)e * 16;
    const float* R = maps + ((size_t)E + (size_t)e) * 16;
    float l[16], r[16];
#pragma unroll
    for (int i = 0; i < 16; i++) { l[i] = L[i]; r[i] = R[i]; }
    if (cls == 1) {
#pragma unroll
      for (int a = 0; a < 4; a++)
#pragma unroll
        for (int b = 0; b < 4; b++)
          val[a * 4 + b] = -(l[0 + a] * r[0 + b] + l[4 + a] * r[4 + b] + l[8 + a] * r[8 + b] + l[12 + a] * r[12 + b]);
    } else {
#pragma unroll
      for (int a = 0; a < 4; a++)
#pragma unroll
        for (int b = 0; b < 4; b++)
          val[a * 4 + b] = -(l[0 + b] * r[0 + a] + l[4 + b] * r[4 + a] + l[8 + b] * r[8 + a] + l[12 + b] * r[12 + a]);
    }
  }

  float* orow = out;
  float* ocol = out + T;
  float* oval = out + 2 * T;
  long long blkbase = 16LL * base + 4LL * k0;
  float cf = (float)(v * 4);
#pragma unroll
  for (int a = 0; a < 4; a++) {
    long long rowbase = blkbase + (long long)a * 4 * cntu;
    float rf = (float)(u * 4 + a);
    if (m == 1) {
      *reinterpret_cast<float4*>(orow + rowbase) = make_float4(rf, rf, rf, rf);
      *reinterpret_cast<float4*>(ocol + rowbase) = make_float4(cf, cf + 1.0f, cf + 2.0f, cf + 3.0f);
      *reinterpret_cast<float4*>(oval + rowbase) =
          make_float4(val[a * 4 + 0], val[a * 4 + 1], val[a * 4 + 2], val[a * 4 + 3]);
    } else {
#pragma unroll
      for (int b = 0; b < 4; b++) {
        long long pos = rowbase + (long long)b * m + j;
        orow[pos] = rf;
        ocol[pos] = cf + (float)b;
        oval[pos] = val[a * 4 + b];
      }
    }
  }
}

extern "C" void kernel_launch(void* const* d_in, const int* in_sizes, int n_in,
                              void* d_out, int out_size, void* d_ws, size_t ws_size,
                              hipStream_t stream) {
  const float* maps = (const float*)d_in[0];
  const int* ei = (const int*)d_in[1];

  long long twoE = (long long)in_sizes[1] / 2;   // edge_index is (2, 2E)
  long long E = twoE / 2;
  long long T = (long long)out_size / 3;         // [rows(T), cols(T), vals(T)], float32
  long long totalBlocks = T / 16;                // n + 2E
  long long n = totalBlocks - twoE;
  if (n < 1 || n > N_MAX || totalBlocks > B_MAX || twoE > B_MAX) return;

  int iE = (int)E, i2E = (int)twoE, iN = (int)n, iB = (int)totalBlocks;
  int g2E = (i2E + THREADS - 1) / THREADS;
  int gD = (4 * iN + THREADS - 1) / THREADS;
  int gSort = (iN + 3) / 4;                      // 4 waves (nodes) per 256-thread block
  int gB = (iB + THREADS - 1) / THREADS;

  hist_kernel<<<g2E, THREADS, 0, stream>>>(ei, iE, i2E);
  scan_kernel<<<2, 1024, 0, stream>>>(iN);
  scatter_fill_kernel<<<g2E, THREADS, 0, stream>>>(ei, iE, i2E);
  diag_place_kernel<<<gD, THREADS, 0, stream>>>(maps, iN);
  sort_kernel<<<gSort, 256, 0, stream>>>(iN);
  emit_kernel<<<gB, THREADS, 0, stream>>>(maps, iE, T, iB, (float*)d_out);
}